// Round 1
// baseline (672.272 us; speedup 1.0000x reference)
//
#include <hip/hip_runtime.h>
#include <hip/hip_bf16.h>

#define S_LEN 4096
#define NH    16
#define DD    128
#define HD    (NH*DD)   // 2048 floats per (s) row
#define QB    64
#define KB    64

typedef __bf16 bf16_t;
typedef bf16_t bf16x8 __attribute__((ext_vector_type(8)));
typedef bf16_t bf16x4 __attribute__((ext_vector_type(4)));
typedef float  f32x4  __attribute__((ext_vector_type(4)));

static __device__ __forceinline__ bf16x8 pack8(float4 a, float4 b, float s) {
  bf16x8 v;
  v[0]=(bf16_t)(a.x*s); v[1]=(bf16_t)(a.y*s); v[2]=(bf16_t)(a.z*s); v[3]=(bf16_t)(a.w*s);
  v[4]=(bf16_t)(b.x*s); v[5]=(bf16_t)(b.y*s); v[6]=(bf16_t)(b.z*s); v[7]=(bf16_t)(b.w*s);
  return v;
}

__global__ __launch_bounds__(256) void attn_fwd(const float* __restrict__ Qg,
                                                const float* __restrict__ Kg,
                                                const float* __restrict__ Vg,
                                                float* __restrict__ Og) {
  const int qt   = blockIdx.x;   // q tile (64 rows)
  const int h    = blockIdx.y;   // head
  const int tid  = threadIdx.x;
  const int wid  = tid >> 6;
  const int lane = tid & 63;
  const int l16  = lane & 15;
  const int lg   = lane >> 4;    // 0..3

  __shared__ alignas(16) bf16_t Ks[KB*DD];      // [64][128] swizzled
  __shared__ alignas(16) bf16_t Vt[DD*KB];      // [128][64] swizzled (V^T)
  __shared__ alignas(16) bf16_t Pl[4][16*KB];   // per-wave [16][64] swizzled

  // ---- load Q fragments, fold scale * log2(e) so softmax uses exp2 ----
  const float qs = 0.08838834764831845f * 1.4426950408889634f;
  bf16x8 qf[4];
  {
    const int qrow = qt*QB + wid*16 + l16;
    const float* qp = Qg + (size_t)qrow*HD + h*DD + lg*8;
    #pragma unroll
    for (int c = 0; c < 4; ++c) {
      float4 a = *(const float4*)(qp + c*32);
      float4 b = *(const float4*)(qp + c*32 + 4);
      qf[c] = pack8(a, b, qs);
    }
  }

  f32x4 acc[8];
  #pragma unroll
  for (int i = 0; i < 8; ++i) acc[i] = (f32x4){0.f,0.f,0.f,0.f};
  float m_run[4] = {-__builtin_inff(), -__builtin_inff(), -__builtin_inff(), -__builtin_inff()};
  float l_run[4] = {0.f, 0.f, 0.f, 0.f};

  char* KsB = (char*)Ks;
  char* VtB = (char*)Vt;
  char* PlB = (char*)&Pl[wid][0];

  for (int kt = 0; kt < S_LEN/KB; ++kt) {
    __syncthreads();   // previous tile's LDS reads done

    // ---- stage K tile [64][128] bf16, XOR-swizzled, b128 writes ----
    #pragma unroll
    for (int it = 0; it < 4; ++it) {
      int idx = it*256 + tid;           // 0..1023, 16 chunks of 8 per row
      int row = idx >> 4;
      int d0  = (idx & 15) << 3;
      const float* gp = Kg + (size_t)(kt*KB + row)*HD + h*DD + d0;
      float4 a = *(const float4*)gp;
      float4 b = *(const float4*)(gp + 4);
      bf16x8 v = pack8(a, b, 1.0f);
      int off = row*256 + ((d0*2) ^ ((row & 7) << 4));
      *(bf16x8*)(KsB + off) = v;
    }
    // ---- stage V^T [128][64]: coalesced dword loads along d, b64 LDS writes ----
    {
      int d  = tid & 127;
      int kg = tid >> 7;                // 0..1
      #pragma unroll
      for (int it = 0; it < 8; ++it) {
        int k0 = it*8 + kg*4;
        const float* gp = Vg + (size_t)(kt*KB + k0)*HD + h*DD + d;
        float f0 = gp[0];
        float f1 = gp[HD];
        float f2 = gp[2*HD];
        float f3 = gp[3*HD];
        bf16x4 v; v[0]=(bf16_t)f0; v[1]=(bf16_t)f1; v[2]=(bf16_t)f2; v[3]=(bf16_t)f3;
        int off = d*128 + ((k0*2) ^ ((d & 7) << 4));
        *(bf16x4*)(VtB + off) = v;
      }
    }
    __syncthreads();

    // ---- S = Q K^T : 16 MFMA per wave ----
    f32x4 sc[4];
    #pragma unroll
    for (int b = 0; b < 4; ++b) sc[b] = (f32x4){0.f,0.f,0.f,0.f};
    #pragma unroll
    for (int b = 0; b < 4; ++b) {
      int row = b*16 + l16;             // k-column this lane supplies
      int rs  = row*256;
      int sw  = (row & 7) << 4;
      #pragma unroll
      for (int c = 0; c < 4; ++c) {
        int d0 = c*32 + lg*8;
        bf16x8 kb = *(const bf16x8*)(KsB + rs + ((d0*2) ^ sw));
        sc[b] = __builtin_amdgcn_mfma_f32_16x16x32_bf16(qf[c], kb, sc[b], 0, 0, 0);
      }
    }

    // ---- online softmax (rows live across lane&15; reduce via shfl_xor) ----
    float pmax[4];
    #pragma unroll
    for (int r = 0; r < 4; ++r) {
      float v = fmaxf(fmaxf(sc[0][r], sc[1][r]), fmaxf(sc[2][r], sc[3][r]));
      v = fmaxf(v, __shfl_xor(v, 1));
      v = fmaxf(v, __shfl_xor(v, 2));
      v = fmaxf(v, __shfl_xor(v, 4));
      v = fmaxf(v, __shfl_xor(v, 8));
      pmax[r] = v;
    }
    float alpha[4];
    #pragma unroll
    for (int r = 0; r < 4; ++r) {
      float mnew = fmaxf(m_run[r], pmax[r]);
      alpha[r] = exp2f(m_run[r] - mnew);   // first tile: exp2(-inf)=0
      m_run[r] = mnew;
    }
    float rsum[4] = {0.f, 0.f, 0.f, 0.f};
    #pragma unroll
    for (int b = 0; b < 4; ++b) {
      int kcol = b*16 + l16;
      #pragma unroll
      for (int r = 0; r < 4; ++r) {
        float p = exp2f(sc[b][r] - m_run[r]);
        rsum[r] += p;
        int q   = lg*4 + r;
        int off = q*128 + ((kcol*2) ^ ((q & 7) << 4));
        *(bf16_t*)(PlB + off) = (bf16_t)p;   // per-wave region; wave-ordered LDS
      }
    }
    #pragma unroll
    for (int r = 0; r < 4; ++r) {
      float v = rsum[r];
      v += __shfl_xor(v, 1);
      v += __shfl_xor(v, 2);
      v += __shfl_xor(v, 4);
      v += __shfl_xor(v, 8);
      l_run[r] = l_run[r]*alpha[r] + v;
    }
    #pragma unroll
    for (int i = 0; i < 8; ++i) {
      #pragma unroll
      for (int r = 0; r < 4; ++r) acc[i][r] *= alpha[r];
    }

    // ---- O += P V : 16 MFMA per wave ----
    #pragma unroll
    for (int ks = 0; ks < 2; ++ks) {
      int k0 = ks*32 + lg*8;
      bf16x8 pa = *(const bf16x8*)(PlB + l16*128 + ((k0*2) ^ ((l16 & 7) << 4)));
      #pragma unroll
      for (int db = 0; db < 8; ++db) {
        int d = db*16 + l16;
        bf16x8 vb = *(const bf16x8*)(VtB + d*128 + ((k0*2) ^ ((d & 7) << 4)));
        acc[db] = __builtin_amdgcn_mfma_f32_16x16x32_bf16(pa, vb, acc[db], 0, 0, 0);
      }
    }
  }

  // ---- epilogue: normalize and store fp32 ----
  const int qrow = qt*QB + wid*16 + lg*4;
  #pragma unroll
  for (int r = 0; r < 4; ++r) {
    float inv = 1.0f / l_run[r];
    float* op = Og + (size_t)(qrow + r)*HD + h*DD + l16;
    #pragma unroll
    for (int db = 0; db < 8; ++db) {
      op[db*16] = acc[db][r] * inv;
    }
  }
}

extern "C" void kernel_launch(void* const* d_in, const int* in_sizes, int n_in,
                              void* d_out, int out_size, void* d_ws, size_t ws_size,
                              hipStream_t stream) {
  const float* Q = (const float*)d_in[0];
  const float* K = (const float*)d_in[1];
  const float* V = (const float*)d_in[2];
  float* O = (float*)d_out;
  dim3 grid(S_LEN/QB, NH);
  attn_fwd<<<grid, 256, 0, stream>>>(Q, K, V, O);
}

// Round 2
// 364.026 us; speedup vs baseline: 1.8468x; 1.8468x over previous
//
#include <hip/hip_runtime.h>
#include <hip/hip_bf16.h>

#define S_LEN 4096
#define NH    16
#define DD    128
#define HD    (NH*DD)   // 2048 floats per (s) row
#define QB    128
#define KB    64
#define NT    (S_LEN/KB)

typedef __bf16 bf16_t;
typedef bf16_t bf16x8 __attribute__((ext_vector_type(8)));
typedef bf16_t bf16x4 __attribute__((ext_vector_type(4)));
typedef float  f32x4  __attribute__((ext_vector_type(4)));

static __device__ __forceinline__ bf16x8 pack8(float4 a, float4 b, float s) {
  bf16x8 v;
  v[0]=(bf16_t)(a.x*s); v[1]=(bf16_t)(a.y*s); v[2]=(bf16_t)(a.z*s); v[3]=(bf16_t)(a.w*s);
  v[4]=(bf16_t)(b.x*s); v[5]=(bf16_t)(b.y*s); v[6]=(bf16_t)(b.z*s); v[7]=(bf16_t)(b.w*s);
  return v;
}

__global__ __launch_bounds__(512, 4) void attn_fwd(const float* __restrict__ Qg,
                                                   const float* __restrict__ Kg,
                                                   const float* __restrict__ Vg,
                                                   float* __restrict__ Og) {
  const int qt   = blockIdx.x;   // q tile (128 rows)
  const int h    = blockIdx.y;   // head
  const int tid  = threadIdx.x;
  const int wid  = tid >> 6;     // 0..7
  const int lane = tid & 63;
  const int l16  = lane & 15;
  const int lg   = lane >> 4;    // 0..3

  __shared__ alignas(16) bf16_t Ks[KB*DD];      // [64][128] swizzled
  __shared__ alignas(16) bf16_t Vt[DD*KB];      // [128][64] swizzled (V^T)
  __shared__ alignas(16) bf16_t Pl[8][16*KB];   // per-wave [16][64] swizzled

  char* KsB = (char*)Ks;
  char* VtB = (char*)Vt;
  char* PlB = (char*)&Pl[wid][0];

  // ---- load Q fragments, fold scale * log2(e) so softmax uses exp2 ----
  const float qs = 0.08838834764831845f * 1.4426950408889634f;
  bf16x8 qf[4];
  {
    const int qrow = qt*QB + wid*16 + l16;
    const float* qp = Qg + (size_t)qrow*HD + h*DD + lg*8;
    #pragma unroll
    for (int c = 0; c < 4; ++c) {
      float4 a = *(const float4*)(qp + c*32);
      float4 b = *(const float4*)(qp + c*32 + 4);
      qf[c] = pack8(a, b, qs);
    }
  }

  // staging geometry (512 threads)
  const int krow = tid >> 4;            // 0..31 (+32 on it=1)
  const int kd0  = (tid & 15) << 3;     // 0,8,..,120
  const int vd   = tid & 127;           // 0..127
  const int vkg  = (tid >> 7) << 2;     // 0,4,8,12

  bf16x8 kreg[2];
  bf16x4 vreg[4];

  // ---- STAGE_LOAD: global -> regs (bf16) for tile kt ----
  auto stage_load = [&](int kt) {
    #pragma unroll
    for (int it = 0; it < 2; ++it) {
      int row = krow + it*32;
      const float* gp = Kg + (size_t)(kt*KB + row)*HD + h*DD + kd0;
      float4 a = *(const float4*)gp;
      float4 b = *(const float4*)(gp + 4);
      kreg[it] = pack8(a, b, 1.0f);
    }
    #pragma unroll
    for (int it = 0; it < 4; ++it) {
      int k0 = it*16 + vkg;
      const float* gp = Vg + (size_t)(kt*KB + k0)*HD + h*DD + vd;
      bf16x4 v;
      v[0]=(bf16_t)gp[0]; v[1]=(bf16_t)gp[HD]; v[2]=(bf16_t)gp[2*HD]; v[3]=(bf16_t)gp[3*HD];
      vreg[it] = v;
    }
  };
  // ---- STAGE_WRITE: regs -> LDS (swizzled) ----
  auto stage_write = [&]() {
    #pragma unroll
    for (int it = 0; it < 2; ++it) {
      int row = krow + it*32;
      int off = row*256 + ((kd0*2) ^ ((row & 7) << 4));
      *(bf16x8*)(KsB + off) = kreg[it];
    }
    #pragma unroll
    for (int it = 0; it < 4; ++it) {
      int k0 = it*16 + vkg;
      int off = vd*128 + ((k0*2) ^ ((vd & 7) << 4));
      *(bf16x4*)(VtB + off) = vreg[it];
    }
  };

  f32x4 acc[8];
  #pragma unroll
  for (int i = 0; i < 8; ++i) acc[i] = (f32x4){0.f,0.f,0.f,0.f};
  float m_run[4] = {-__builtin_inff(), -__builtin_inff(), -__builtin_inff(), -__builtin_inff()};
  float l_run[4] = {0.f, 0.f, 0.f, 0.f};

  // prologue: stage tile 0
  stage_load(0);
  stage_write();
  __syncthreads();

  for (int kt = 0; kt < NT; ++kt) {
    // ---- issue next tile's global loads EARLY (clamped, branchless) ----
    int ktn = kt + 1 < NT ? kt + 1 : NT - 1;
    stage_load(ktn);

    // ---- S = Q K^T : 16 MFMA per wave ----
    f32x4 sc[4];
    #pragma unroll
    for (int b = 0; b < 4; ++b) sc[b] = (f32x4){0.f,0.f,0.f,0.f};
    #pragma unroll
    for (int b = 0; b < 4; ++b) {
      int row = b*16 + l16;             // k-column this lane supplies
      int rs  = row*256;
      int sw  = (row & 7) << 4;
      #pragma unroll
      for (int c = 0; c < 4; ++c) {
        int d0 = c*32 + lg*8;
        bf16x8 kb = *(const bf16x8*)(KsB + rs + ((d0*2) ^ sw));
        sc[b] = __builtin_amdgcn_mfma_f32_16x16x32_bf16(qf[c], kb, sc[b], 0, 0, 0);
      }
    }

    // ---- online softmax (rows live across lane&15; reduce via shfl_xor) ----
    float pmax[4];
    #pragma unroll
    for (int r = 0; r < 4; ++r) {
      float v = fmaxf(fmaxf(sc[0][r], sc[1][r]), fmaxf(sc[2][r], sc[3][r]));
      v = fmaxf(v, __shfl_xor(v, 1));
      v = fmaxf(v, __shfl_xor(v, 2));
      v = fmaxf(v, __shfl_xor(v, 4));
      v = fmaxf(v, __shfl_xor(v, 8));
      pmax[r] = v;
    }
    float alpha[4];
    #pragma unroll
    for (int r = 0; r < 4; ++r) {
      float mnew = fmaxf(m_run[r], pmax[r]);
      alpha[r] = exp2f(m_run[r] - mnew);   // first tile: exp2(-inf)=0
      m_run[r] = mnew;
    }
    float rsum[4] = {0.f, 0.f, 0.f, 0.f};
    #pragma unroll
    for (int b = 0; b < 4; ++b) {
      int kcol = b*16 + l16;
      #pragma unroll
      for (int r = 0; r < 4; ++r) {
        float p = exp2f(sc[b][r] - m_run[r]);
        rsum[r] += p;
        int q   = lg*4 + r;
        int off = q*128 + ((kcol*2) ^ ((q & 7) << 4));
        *(bf16_t*)(PlB + off) = (bf16_t)p;   // per-wave region; wave-ordered LDS
      }
    }
    #pragma unroll
    for (int r = 0; r < 4; ++r) {
      float v = rsum[r];
      v += __shfl_xor(v, 1);
      v += __shfl_xor(v, 2);
      v += __shfl_xor(v, 4);
      v += __shfl_xor(v, 8);
      l_run[r] = l_run[r]*alpha[r] + v;
    }
    #pragma unroll
    for (int i = 0; i < 8; ++i) {
      #pragma unroll
      for (int r = 0; r < 4; ++r) acc[i][r] *= alpha[r];
    }

    // ---- O += P V : 16 MFMA per wave ----
    #pragma unroll
    for (int ks = 0; ks < 2; ++ks) {
      int k0 = ks*32 + lg*8;
      bf16x8 pa = *(const bf16x8*)(PlB + l16*128 + ((k0*2) ^ ((l16 & 7) << 4)));
      #pragma unroll
      for (int db = 0; db < 8; ++db) {
        int d = db*16 + l16;
        bf16x8 vb = *(const bf16x8*)(VtB + d*128 + ((k0*2) ^ ((d & 7) << 4)));
        acc[db] = __builtin_amdgcn_mfma_f32_16x16x32_bf16(pa, vb, acc[db], 0, 0, 0);
      }
    }

    // ---- WRITE_LATE: all LDS reads of this tile done -> overwrite ----
    __syncthreads();
    stage_write();
    __syncthreads();
  }

  // ---- epilogue: normalize and store fp32 ----
  const int qrow = qt*QB + wid*16 + lg*4;
  #pragma unroll
  for (int r = 0; r < 4; ++r) {
    float inv = 1.0f / l_run[r];
    float* op = Og + (size_t)(qrow + r)*HD + h*DD + l16;
    #pragma unroll
    for (int db = 0; db < 8; ++db) {
      op[db*16] = acc[db][r] * inv;
    }
  }
}

extern "C" void kernel_launch(void* const* d_in, const int* in_sizes, int n_in,
                              void* d_out, int out_size, void* d_ws, size_t ws_size,
                              hipStream_t stream) {
  const float* Q = (const float*)d_in[0];
  const float* K = (const float*)d_in[1];
  const float* V = (const float*)d_in[2];
  float* O = (float*)d_out;
  dim3 grid(S_LEN/QB, NH);
  attn_fwd<<<grid, 512, 0, stream>>>(Q, K, V, O);
}

// Round 3
// 239.417 us; speedup vs baseline: 2.8080x; 1.5205x over previous
//
#include <hip/hip_runtime.h>
#include <hip/hip_bf16.h>

#define S_LEN 4096
#define NH    16
#define DD    128
#define HD    (NH*DD)   // 2048 floats per (s) row
#define QB    128
#define KB    64
#define NT    (S_LEN/KB)

typedef __bf16 bf16_t;
typedef bf16_t bf16x8 __attribute__((ext_vector_type(8)));
typedef bf16_t bf16x4 __attribute__((ext_vector_type(4)));
typedef float  f32x4  __attribute__((ext_vector_type(4)));

static __device__ __forceinline__ bf16x8 pack8(float4 a, float4 b, float s) {
  bf16x8 v;
  v[0]=(bf16_t)(a.x*s); v[1]=(bf16_t)(a.y*s); v[2]=(bf16_t)(a.z*s); v[3]=(bf16_t)(a.w*s);
  v[4]=(bf16_t)(b.x*s); v[5]=(bf16_t)(b.y*s); v[6]=(bf16_t)(b.z*s); v[7]=(bf16_t)(b.w*s);
  return v;
}

__global__ __launch_bounds__(512, 4) void attn_fwd(const float* __restrict__ Qg,
                                                   const float* __restrict__ Kg,
                                                   const float* __restrict__ Vg,
                                                   float* __restrict__ Og) {
  const int qt   = blockIdx.x;   // q tile (128 rows)
  const int h    = blockIdx.y;   // head
  const int tid  = threadIdx.x;
  const int wid  = tid >> 6;     // 0..7
  const int lane = tid & 63;
  const int l16  = lane & 15;
  const int lg   = lane >> 4;    // 0..3

  // double-buffered K [64][128] and V^T [128][64] (permuted cols), both swizzled
  __shared__ alignas(16) bf16_t Ks[2][KB*DD];
  __shared__ alignas(16) bf16_t Vt[2][DD*KB];

  // ---- Q fragments (B-operand of swapped QK^T); fold scale*log2e ----
  const float qs = 0.08838834764831845f * 1.4426950408889634f;
  bf16x8 qf[4];
  {
    const int qrow = qt*QB + wid*16 + l16;
    const float* qp = Qg + (size_t)qrow*HD + h*DD + lg*8;
    #pragma unroll
    for (int c = 0; c < 4; ++c) {
      float4 a = *(const float4*)(qp + c*32);
      float4 b = *(const float4*)(qp + c*32 + 4);
      qf[c] = pack8(a, b, qs);
    }
  }

  // staging geometry (512 threads)
  const int krow = tid >> 4;            // 0..31 (+32 on it=1)
  const int kd0  = (tid & 15) << 3;     // 0,8,..,120
  const int vd   = tid & 127;           // 0..127
  const int vkg  = (tid >> 7) << 2;     // 0,4,8,12

  bf16x8 kreg[2];
  bf16x4 vreg[4];

  // ---- STAGE_LOAD: global -> regs (bf16) for tile kt ----
  auto stage_load = [&](int kt) {
    #pragma unroll
    for (int it = 0; it < 2; ++it) {
      int row = krow + it*32;
      const float* gp = Kg + (size_t)(kt*KB + row)*HD + h*DD + kd0;
      float4 a = *(const float4*)gp;
      float4 b = *(const float4*)(gp + 4);
      kreg[it] = pack8(a, b, 1.0f);
    }
    #pragma unroll
    for (int it = 0; it < 4; ++it) {
      int k0 = it*16 + vkg;
      const float* gp = Vg + (size_t)(kt*KB + k0)*HD + h*DD + vd;
      bf16x4 v;
      v[0]=(bf16_t)gp[0]; v[1]=(bf16_t)gp[HD]; v[2]=(bf16_t)gp[2*HD]; v[3]=(bf16_t)gp[3*HD];
      vreg[it] = v;
    }
  };
  // ---- STAGE_WRITE: regs -> LDS buffer b (swizzled; V cols permuted) ----
  auto stage_write = [&](int b) {
    char* KsB = (char*)&Ks[b][0];
    char* VtB = (char*)&Vt[b][0];
    #pragma unroll
    for (int it = 0; it < 2; ++it) {
      int row = krow + it*32;
      int off = row*256 + ((kd0*2) ^ ((row & 7) << 4));
      *(bf16x8*)(KsB + off) = kreg[it];
    }
    // V: pcol(k) = 32*(k>>5) + ((k>>2)&3)*8 + ((k&16)?4:0) + (k&3)
    // pairs (vreg[0],vreg[1]) -> pcol base vkg*2; (vreg[2],vreg[3]) -> 32+vkg*2
    {
      bf16x8 w0, w1;
      #pragma unroll
      for (int j = 0; j < 4; ++j) { w0[j]=vreg[0][j]; w0[4+j]=vreg[1][j];
                                    w1[j]=vreg[2][j]; w1[4+j]=vreg[3][j]; }
      int sw = (vd & 7) << 4;
      *(bf16x8*)(VtB + vd*128 + (( vkg*4      ) ^ sw)) = w0;
      *(bf16x8*)(VtB + vd*128 + ((64 + vkg*4  ) ^ sw)) = w1;
    }
  };

  f32x4 acc[8];
  #pragma unroll
  for (int i = 0; i < 8; ++i) acc[i] = (f32x4){0.f,0.f,0.f,0.f};
  float m_run = -__builtin_inff();
  float l_run = 0.f;

  // prologue
  stage_load(0);
  stage_write(0);
  stage_load(NT > 1 ? 1 : 0);
  __syncthreads();

  for (int kt = 0; kt < NT; ++kt) {
    const int cur = kt & 1;
    char* KsB = (char*)&Ks[cur][0];
    char* VtB = (char*)&Vt[cur][0];

    // ---- S^T = K Q^T : 16 MFMA (A = K rows, B = Q) ----
    f32x4 sc[4];
    #pragma unroll
    for (int b = 0; b < 4; ++b) sc[b] = (f32x4){0.f,0.f,0.f,0.f};
    #pragma unroll
    for (int b = 0; b < 4; ++b) {
      int row = b*16 + l16;             // K row this lane supplies (A-row)
      int rs  = row*256;
      int sw  = (row & 7) << 4;
      #pragma unroll
      for (int c = 0; c < 4; ++c) {
        int d0 = c*32 + lg*8;
        bf16x8 kb = *(const bf16x8*)(KsB + rs + ((d0*2) ^ sw));
        sc[b] = __builtin_amdgcn_mfma_f32_16x16x32_bf16(kb, qf[c], sc[b], 0, 0, 0);
      }
    }
    // lane now holds S^T[k = b*16 + lg*4 + r][q = l16] in sc[b][r]

    // ---- online softmax, fully in-register per q-row ----
    float pmax;
    {
      float t0 = fmaxf(fmaxf(sc[0][0], sc[0][1]), fmaxf(sc[0][2], sc[0][3]));
      float t1 = fmaxf(fmaxf(sc[1][0], sc[1][1]), fmaxf(sc[1][2], sc[1][3]));
      float t2 = fmaxf(fmaxf(sc[2][0], sc[2][1]), fmaxf(sc[2][2], sc[2][3]));
      float t3 = fmaxf(fmaxf(sc[3][0], sc[3][1]), fmaxf(sc[3][2], sc[3][3]));
      pmax = fmaxf(fmaxf(t0, t1), fmaxf(t2, t3));
      pmax = fmaxf(pmax, __shfl_xor(pmax, 16));
      pmax = fmaxf(pmax, __shfl_xor(pmax, 32));
    }
    float mnew  = fmaxf(m_run, pmax);
    float alpha = exp2f(m_run - mnew);   // first tile: exp2(-inf)=0
    m_run = mnew;

    float rsum = 0.f;
    bf16x4 pb[4];
    #pragma unroll
    for (int b = 0; b < 4; ++b) {
      #pragma unroll
      for (int r = 0; r < 4; ++r) {
        float p = exp2f(sc[b][r] - mnew);
        rsum += p;
        pb[b][r] = (bf16_t)p;
      }
    }
    rsum += __shfl_xor(rsum, 16);
    rsum += __shfl_xor(rsum, 32);
    l_run = l_run*alpha + rsum;

    #pragma unroll
    for (int i = 0; i < 8; ++i) {
      #pragma unroll
      for (int r = 0; r < 4; ++r) acc[i][r] *= alpha;
    }

    // ---- O^T += V^T P^T : 16 MFMA (A = V^T from LDS, B = P in-register) ----
    #pragma unroll
    for (int ks = 0; ks < 2; ++ks) {
      bf16x8 pp;
      #pragma unroll
      for (int j = 0; j < 4; ++j) { pp[j] = pb[2*ks][j]; pp[4+j] = pb[2*ks+1][j]; }
      #pragma unroll
      for (int db = 0; db < 8; ++db) {
        int d = db*16 + l16;
        bf16x8 va = *(const bf16x8*)(VtB + d*128 + ((64*ks + lg*16) ^ ((d & 7) << 4)));
        acc[db] = __builtin_amdgcn_mfma_f32_16x16x32_bf16(va, pp, acc[db], 0, 0, 0);
      }
    }

    // ---- fill other buffer for kt+1 (loaded last iter), issue loads kt+2 ----
    if (kt + 1 < NT) {
      stage_write(cur ^ 1);
      int ktn = kt + 2 < NT ? kt + 2 : NT - 1;
      stage_load(ktn);
      __syncthreads();
    }
  }

  // ---- epilogue: normalize, store O (lane: q=l16, d=db*16+lg*4+r) ----
  const int qrow = qt*QB + wid*16 + l16;
  const float inv = 1.0f / l_run;
  float* op = Og + (size_t)qrow*HD + h*DD + lg*4;
  #pragma unroll
  for (int db = 0; db < 8; ++db) {
    float4 o;
    o.x = acc[db][0]*inv; o.y = acc[db][1]*inv;
    o.z = acc[db][2]*inv; o.w = acc[db][3]*inv;
    *(float4*)(op + db*16) = o;
  }
}

extern "C" void kernel_launch(void* const* d_in, const int* in_sizes, int n_in,
                              void* d_out, int out_size, void* d_ws, size_t ws_size,
                              hipStream_t stream) {
  const float* Q = (const float*)d_in[0];
  const float* K = (const float*)d_in[1];
  const float* V = (const float*)d_in[2];
  float* O = (float*)d_out;
  dim3 grid(S_LEN/QB, NH);
  attn_fwd<<<grid, 512, 0, stream>>>(Q, K, V, O);
}

// Round 4
// 209.717 us; speedup vs baseline: 3.2056x; 1.1416x over previous
//
#include <hip/hip_runtime.h>
#include <hip/hip_bf16.h>

#define S_LEN 4096
#define NH    16
#define DD    128
#define HD    2048
#define QB    128
#define KB    64
#define NT    (S_LEN/KB)

typedef __bf16 bf16_t;
typedef bf16_t bf16x8 __attribute__((ext_vector_type(8)));
typedef bf16_t bf16x4 __attribute__((ext_vector_type(4)));
typedef float  f32x4  __attribute__((ext_vector_type(4)));

static __device__ __forceinline__ bf16x8 pack8(float4 a, float4 b, float s) {
  bf16x8 v;
  v[0]=(bf16_t)(a.x*s); v[1]=(bf16_t)(a.y*s); v[2]=(bf16_t)(a.z*s); v[3]=(bf16_t)(a.w*s);
  v[4]=(bf16_t)(b.x*s); v[5]=(bf16_t)(b.y*s); v[6]=(bf16_t)(b.z*s); v[7]=(bf16_t)(b.w*s);
  return v;
}

static __device__ __forceinline__ void gload_lds16(const void* g, void* l) {
  __builtin_amdgcn_global_load_lds((const __attribute__((address_space(1))) void*)g,
                                   (__attribute__((address_space(3))) void*)l, 16, 0, 0);
}

// ---- pre-pass: K fp32 [s][h][d] -> bf16 [h][s][chunk-XOR-swizzled d] ----
__global__ __launch_bounds__(256) void prep_k(const float* __restrict__ Kg,
                                              bf16_t* __restrict__ Kp) {
  int idx = blockIdx.x * 256 + threadIdx.x;   // one 16B out-chunk each
  int jp = idx & 15;
  int s  = (idx >> 4) & (S_LEN - 1);
  int h  = idx >> 16;
  int jl = jp ^ (s & 7);
  const float* src = Kg + (size_t)s*HD + h*DD + jl*8;
  float4 a = *(const float4*)src;
  float4 b = *(const float4*)(src + 4);
  *(bf16x8*)(Kp + ((size_t)h*S_LEN + s)*DD + jp*8) = pack8(a, b, 1.0f);
}

// ---- pre-pass: V fp32 [s][h][d] -> bf16 [h][kt][d][perm+swizzled k] ----
__global__ __launch_bounds__(256) void prep_v(const float* __restrict__ Vg,
                                              bf16_t* __restrict__ Vp) {
  int kt = blockIdx.x;
  int h  = blockIdx.y;
  int tid = threadIdx.x;
  __shared__ bf16_t tile[KB][DD + 8];
  #pragma unroll
  for (int it = 0; it < 8; ++it) {
    int lin4 = it*256 + tid;          // 2048 float4s
    int r  = lin4 >> 5;
    int dc = (lin4 & 31) * 4;
    float4 a = *(const float4*)(Vg + (size_t)(kt*KB + r)*HD + h*DD + dc);
    tile[r][dc+0]=(bf16_t)a.x; tile[r][dc+1]=(bf16_t)a.y;
    tile[r][dc+2]=(bf16_t)a.z; tile[r][dc+3]=(bf16_t)a.w;
  }
  __syncthreads();
  bf16_t* out = Vp + (size_t)(h*NT + kt)*DD*KB;
  #pragma unroll
  for (int it = 0; it < 4; ++it) {
    int cid = it*256 + tid;           // 1024 out-chunks
    int d  = cid >> 3;
    int jp = cid & 7;
    bf16x8 v;
    #pragma unroll
    for (int m = 0; m < 8; ++m) {
      int c = ((jp ^ (d & 7)) << 3) + m;             // logical col
      int k = 32*(c>>5) + 16*((c>>2)&1) + 4*((c>>3)&3) + (c&3);  // MFMA k-slot bijection
      v[m] = tile[k][d];
    }
    *(bf16x8*)(out + d*KB + jp*8) = v;
  }
}

__global__ __launch_bounds__(512, 4) void attn_fwd(const float* __restrict__ Qg,
                                                   const bf16_t* __restrict__ Kp,
                                                   const bf16_t* __restrict__ Vp,
                                                   float* __restrict__ Og) {
  const int qt   = blockIdx.x;
  const int h    = blockIdx.y;
  const int tid  = threadIdx.x;
  const int wid  = tid >> 6;
  const int lane = tid & 63;
  const int l16  = lane & 15;
  const int lg   = lane >> 4;

  __shared__ alignas(16) bf16_t Ks[2][KB*DD];   // 16KB each, swizzled contents
  __shared__ alignas(16) bf16_t Vt[2][DD*KB];   // 16KB each, perm+swizzled

  // ---- Q fragments (B-operand of swapped QK^T); fold scale*log2e ----
  const float qs = 0.08838834764831845f * 1.4426950408889634f;
  bf16x8 qf[4];
  {
    const int qrow = qt*QB + wid*16 + l16;
    const float* qp = Qg + (size_t)qrow*HD + h*DD + lg*8;
    #pragma unroll
    for (int c = 0; c < 4; ++c) {
      float4 a = *(const float4*)(qp + c*32);
      float4 b = *(const float4*)(qp + c*32 + 4);
      qf[c] = pack8(a, b, qs);
    }
  }
  asm volatile("" ::: "memory");   // keep Q loads above the staging issues

  // ---- staging: pure linear global->LDS DMA (4x16B per thread per tile) ----
  const int lo = wid*1024 + lane*16;
  auto issue = [&](int kt) {
    int b = kt & 1;
    const char* kg = (const char*)(Kp + ((size_t)h*S_LEN + kt*KB)*DD);
    const char* vg = (const char*)(Vp + (size_t)(h*NT + kt)*DD*KB);
    char* kl = (char*)&Ks[b][0];
    char* vl = (char*)&Vt[b][0];
    gload_lds16(kg + lo,        kl + lo);
    gload_lds16(kg + lo + 8192, kl + lo + 8192);
    gload_lds16(vg + lo,        vl + lo);
    gload_lds16(vg + lo + 8192, vl + lo + 8192);
  };

  f32x4 acc[8];
  #pragma unroll
  for (int i = 0; i < 8; ++i) acc[i] = (f32x4){0.f,0.f,0.f,0.f};
  float m_run = -__builtin_inff();
  float l_run = 0.f;

  issue(0);
  issue(1);

  for (int kt = 0; kt < NT; ++kt) {
    if (kt == NT-1) { asm volatile("s_waitcnt vmcnt(0)" ::: "memory"); }
    else            { asm volatile("s_waitcnt vmcnt(4)" ::: "memory"); }
    __builtin_amdgcn_s_barrier();
    asm volatile("" ::: "memory");

    const int cur = kt & 1;
    const char* KsB = (const char*)&Ks[cur][0];
    const char* VtB = (const char*)&Vt[cur][0];

    // ---- S^T = K Q^T : 16 MFMA ----
    f32x4 sc[4];
    #pragma unroll
    for (int b = 0; b < 4; ++b) sc[b] = (f32x4){0.f,0.f,0.f,0.f};
    __builtin_amdgcn_s_setprio(1);
    #pragma unroll
    for (int b = 0; b < 4; ++b) {
      int row = b*16 + l16;
      int rs  = row*256;
      int sw  = (row & 7) << 4;
      #pragma unroll
      for (int c = 0; c < 4; ++c) {
        int d0 = c*32 + lg*8;
        bf16x8 kb = *(const bf16x8*)(KsB + rs + ((d0*2) ^ sw));
        sc[b] = __builtin_amdgcn_mfma_f32_16x16x32_bf16(kb, qf[c], sc[b], 0, 0, 0);
      }
    }
    __builtin_amdgcn_s_setprio(0);
    // lane holds S^T[k = b*16 + lg*4 + r][q = l16]

    // ---- online softmax with defer-rescale (T13, THR=8 in exp2 units) ----
    float pmax;
    {
      float t0 = fmaxf(fmaxf(sc[0][0], sc[0][1]), fmaxf(sc[0][2], sc[0][3]));
      float t1 = fmaxf(fmaxf(sc[1][0], sc[1][1]), fmaxf(sc[1][2], sc[1][3]));
      float t2 = fmaxf(fmaxf(sc[2][0], sc[2][1]), fmaxf(sc[2][2], sc[2][3]));
      float t3 = fmaxf(fmaxf(sc[3][0], sc[3][1]), fmaxf(sc[3][2], sc[3][3]));
      pmax = fmaxf(fmaxf(t0, t1), fmaxf(t2, t3));
      pmax = fmaxf(pmax, __shfl_xor(pmax, 16));
      pmax = fmaxf(pmax, __shfl_xor(pmax, 32));
    }
    if (!__all(pmax - m_run <= 8.0f)) {
      float mnew  = fmaxf(m_run, pmax);
      float alpha = exp2f(m_run - mnew);    // first tile: exp2(-inf)=0
      m_run = mnew;
      l_run *= alpha;
      #pragma unroll
      for (int i = 0; i < 8; ++i) {
        #pragma unroll
        for (int r = 0; r < 4; ++r) acc[i][r] *= alpha;
      }
    }

    float rsum = 0.f;
    bf16x4 pb[4];
    #pragma unroll
    for (int b = 0; b < 4; ++b) {
      #pragma unroll
      for (int r = 0; r < 4; ++r) {
        float p = exp2f(sc[b][r] - m_run);   // bounded by 2^8
        rsum += p;
        pb[b][r] = (bf16_t)p;
      }
    }
    rsum += __shfl_xor(rsum, 16);
    rsum += __shfl_xor(rsum, 32);
    l_run += rsum;

    // ---- O^T += V^T P^T : 16 MFMA (A = V^T from LDS, B = P in-register) ----
    __builtin_amdgcn_s_setprio(1);
    #pragma unroll
    for (int ks = 0; ks < 2; ++ks) {
      bf16x8 pp;
      #pragma unroll
      for (int j = 0; j < 4; ++j) { pp[j] = pb[2*ks][j]; pp[4+j] = pb[2*ks+1][j]; }
      #pragma unroll
      for (int db = 0; db < 8; ++db) {
        int d = db*16 + l16;
        bf16x8 va = *(const bf16x8*)(VtB + d*128 + ((64*ks + lg*16) ^ ((d & 7) << 4)));
        acc[db] = __builtin_amdgcn_mfma_f32_16x16x32_bf16(va, pp, acc[db], 0, 0, 0);
      }
    }
    __builtin_amdgcn_s_setprio(0);

    __builtin_amdgcn_s_barrier();     // all reads of buf[cur] done
    asm volatile("" ::: "memory");
    if (kt + 2 < NT) issue(kt + 2);   // overwrites buf[cur] asynchronously
  }

  // ---- epilogue: normalize, store O (lane: q=l16, d=db*16+lg*4+r) ----
  const int qrow = qt*QB + wid*16 + l16;
  const float inv = 1.0f / l_run;
  float* op = Og + (size_t)qrow*HD + h*DD + lg*4;
  #pragma unroll
  for (int db = 0; db < 8; ++db) {
    float4 o;
    o.x = acc[db][0]*inv; o.y = acc[db][1]*inv;
    o.z = acc[db][2]*inv; o.w = acc[db][3]*inv;
    *(float4*)(op + db*16) = o;
  }
}

extern "C" void kernel_launch(void* const* d_in, const int* in_sizes, int n_in,
                              void* d_out, int out_size, void* d_ws, size_t ws_size,
                              hipStream_t stream) {
  const float* Q = (const float*)d_in[0];
  const float* K = (const float*)d_in[1];
  const float* V = (const float*)d_in[2];
  float* O = (float*)d_out;
  bf16_t* Kp = (bf16_t*)d_ws;                       // 16.78 MB
  bf16_t* Vp = Kp + (size_t)NH*S_LEN*DD;            // 16.78 MB
  prep_k<<<dim3(NH*S_LEN*16/256), 256, 0, stream>>>(K, Kp);
  prep_v<<<dim3(NT, NH), 256, 0, stream>>>(V, Vp);
  dim3 grid(S_LEN/QB, NH);
  attn_fwd<<<grid, 512, 0, stream>>>(Q, Kp, Vp, O);
}